// Round 7
// baseline (261.164 us; speedup 1.0000x reference)
//
#include <hip/hip_runtime.h>
#include <hip/hip_fp16.h>

// CTC loss forward, sum over batch — FUSED single kernel.
// One block per batch element b: 15 waves (960 threads).
//   wave 0      : alpha recurrence (linear domain, exact pow2 rescale)
//   waves 1..14 : producers — load logp row (coalesced), stage fp16 row in
//                 LDS scratch, gather ext[] columns, exp, write a 204-float
//                 emission row into an LDS ring; publish per-row ready flag.
// All synchronization is intra-block via LDS (ready flags + consumer progress
// counter) — no inter-block ordering assumptions, no global workspace.

constexpr int Bc = 32, Cc = 1000, Sc = 100;
constexpr int L = 2 * Sc + 1;   // 201
constexpr int NP = 14;          // producer waves
constexpr int RING = 40;        // ring depth (rows)
constexpr int RSF = 204;        // ring row stride (floats), 816B = 51*16B
constexpr float OFF = 7.0f;     // emission log-offset
constexpr float LOG2E = 1.4426950408889634f;
constexpr float LN2 = 0.6931471805599453f;

// DPP wave_shr:1 — lane i reads lane i-1; lane 0 gets 0 (bound_ctrl).
__device__ __forceinline__ float dpp_shr1(float x) {
    return __int_as_float(
        __builtin_amdgcn_update_dpp(0, __float_as_int(x), 0x138, 0xF, 0xF, true));
}

// Wave-wide max of NONNEGATIVE values via gfx9 DPP ladder; result uniform.
__device__ __forceinline__ float wave_max_nonneg(float x) {
#define DPP_MAX(ctrl)                                                        \
    x = fmaxf(x, __int_as_float(__builtin_amdgcn_update_dpp(                 \
                     0, __float_as_int(x), (ctrl), 0xF, 0xF, true)))
    DPP_MAX(0x111); DPP_MAX(0x112); DPP_MAX(0x114);
    DPP_MAX(0x118); DPP_MAX(0x142); DPP_MAX(0x143);
#undef DPP_MAX
    return __int_as_float(__builtin_amdgcn_readlane(__float_as_int(x), 63));
}

// Issue 4x dwordx4 (64B) for this lane's slice of a logp row; results invalid
// until wait4() below. vmcnt discipline: ONLY these asm loads are in flight
// inside the producer loop (all other loop memory traffic is LDS/lgkm).
__device__ __forceinline__ void issue_row(uint4& r0, uint4& r1, uint4& r2,
                                          uint4& r3, const float* p) {
    asm volatile(
        "global_load_dwordx4 %0, %4, off\n\t"
        "global_load_dwordx4 %1, %4, off offset:16\n\t"
        "global_load_dwordx4 %2, %4, off offset:32\n\t"
        "global_load_dwordx4 %3, %4, off offset:48"
        : "=v"(r0), "=v"(r1), "=v"(r2), "=v"(r3)
        : "v"(p));
}
// Wait until only the newest 4 loads remain outstanding (the other row's).
// NOTE: gfx950 inline asm cannot tie 128-bit operands ("tied indirect register
// inputs") — tie the 16 scalar components instead (32-bit ties are supported).
__device__ __forceinline__ void wait4(uint4& r0, uint4& r1, uint4& r2, uint4& r3) {
    asm volatile("s_waitcnt vmcnt(4)"
                 : "+v"(r0.x), "+v"(r0.y), "+v"(r0.z), "+v"(r0.w),
                   "+v"(r1.x), "+v"(r1.y), "+v"(r1.z), "+v"(r1.w),
                   "+v"(r2.x), "+v"(r2.y), "+v"(r2.z), "+v"(r2.w),
                   "+v"(r3.x), "+v"(r3.y), "+v"(r3.z), "+v"(r3.w));
}

__global__ void __launch_bounds__(960, 4) ctc_fused(
        const float* __restrict__ logp, const int* __restrict__ targets,
        const int* __restrict__ input_lens, const int* __restrict__ target_lens,
        float* __restrict__ out) {
    __shared__ __half scratch[NP][1024];   // fp16 logp rows, one slot/producer
    __shared__ float ring[RING * RSF];     // emission rows p' = exp(logp+OFF)
    __shared__ int flags[RING];            // row id stored in slot (init -1)
    __shared__ int consp;                  // consumer progress (last row done)

    const int b = blockIdx.x;
    const int tid = threadIdx.x;
    const int wid = tid >> 6;
    const int lane = tid & 63;
    const int Tb = input_lens[b];
    const int tl = target_lens[b];

    if (tid < RING) flags[tid] = -1;
    if (tid == RING) consp = -1;
    __syncthreads();

    volatile int* vflags = flags;
    volatile int* vconsp = &consp;

    if (wid == 0) {
        // ================= consumer: alpha recurrence =================
        const int col = (lane <= 50) ? 4 * lane : 200;
        const int lcl = (lane <= 50) ? lane : 50;

        // skip masks for odd positions col+1, col+3 (even = blank, never skips)
        float m1 = 0.f, m3 = 0.f;
        if (lane <= 50) {
            const int l1 = col + 1;
            if (l1 >= 3 && l1 < L) {
                const int s = (l1 - 1) >> 1;
                if (targets[b * Sc + s] != targets[b * Sc + s - 1]) m1 = 1.f;
            }
            const int l3 = col + 3;
            if (l3 >= 3 && l3 < L) {
                const int s = (l3 - 1) >> 1;
                if (targets[b * Sc + s] != targets[b * Sc + s - 1]) m3 = 1.f;
            }
        }

        float a0 = 0.f, a1 = 0.f, a2 = 0.f, a3 = 0.f;
        int esum = 0;

#define CTC_STEP(P_)                                  \
    do {                                              \
        const float am1 = dpp_shr1(a3);               \
        const float s01 = a0 + a1;                    \
        const float s23 = a2 + a3;                    \
        const float n0 = (a0 + am1) * (P_).x;         \
        const float n1 = fmaf(am1, m1, s01) * (P_).y; \
        const float n2 = (a1 + a2) * (P_).z;          \
        const float n3 = fmaf(a1, m3, s23) * (P_).w;  \
        a0 = n0; a1 = n1; a2 = n2; a3 = n3;           \
    } while (0)

#define CTC_RESCALE()                                                          \
    do {                                                                       \
        const float mx = wave_max_nonneg(fmaxf(fmaxf(a0, a1), fmaxf(a2, a3))); \
        const unsigned bits = __float_as_uint(mx);                             \
        if (bits != 0u) {                                                      \
            const int e = (int)((bits >> 23) & 0xFFu) - 127;                   \
            const float sc = __uint_as_float((unsigned)(127 - e) << 23);       \
            a0 *= sc; a1 *= sc; a2 *= sc; a3 *= sc;                            \
            esum += e;                                                         \
        }                                                                      \
    } while (0)

        // t=0 init row
        while (vflags[0] != 0) {}
        __threadfence_block();
        {
            const float4 q0 = *(const float4*)&ring[4 * lcl];
            if (lane == 0) { a0 = q0.x; a1 = q0.y; }
        }

        int t = 1, since = 0;
        while (t + 8 <= Tb) {
            // wait for the 8 rows of this batch (lanes check one each)
            const int k = lane & 7;
            const int idx = (t + k) % RING;
            const int want = t + k;
            while (!__all(vflags[idx] == want)) {}
            __threadfence_block();
            float4 q[8];
#pragma unroll
            for (int j = 0; j < 8; ++j)
                q[j] = *(const float4*)&ring[((t + j) % RING) * RSF + 4 * lcl];
#pragma unroll
            for (int j = 0; j < 8; ++j) CTC_STEP(q[j]);
            since += 8;
            if (since >= 16) { CTC_RESCALE(); since = 0; }
            if (lane == 0) *vconsp = t + 7;   // release ring slots
            t += 8;
        }
        for (; t < Tb; ++t) {  // tail (<8 rows)
            const int idx = t % RING;
            while (vflags[idx] != t) {}
            __threadfence_block();
            const float4 q = *(const float4*)&ring[idx * RSF + 4 * lcl];
            CTC_STEP(q);
        }
#undef CTC_STEP

        // final: sum alpha at positions 2*tl and 2*tl-1
        const int e1 = 2 * tl, e2 = 2 * tl - 1;
        float contrib = 0.f;
        if (lane <= 50) {
            if (col + 0 == e1 || col + 0 == e2) contrib += a0;
            if (col + 1 == e1 || col + 1 == e2) contrib += a1;
            if (col + 2 == e1 || col + 2 == e2) contrib += a2;
            if (col + 3 == e1 || col + 3 == e2) contrib += a3;
        }
#pragma unroll
        for (int off = 32; off; off >>= 1) contrib += __shfl_xor(contrib, off);

        if (lane == 0) {
            const float logalpha =
                logf(contrib) + (float)esum * LN2 - OFF * (float)Tb;
            float loss = -logalpha;
            if (!(loss < 0.5e30f)) loss = 0.f;  // zero_infinity (NaN/inf too)
            atomicAdd(out, loss);
        }
    } else {
        // ================= producers =================
        const int p = wid - 1;  // 0..NP-1, owns scratch[p]; rows t ≡ p (mod NP)

        // fixed gather columns for this lane (4 positions g = lane + 64j)
        int cof[4];
#pragma unroll
        for (int j = 0; j < 4; ++j) {
            const int g = lane + 64 * j;
            int c = 0;
            if (g < L && (g & 1)) c = targets[b * Sc + (g >> 1)];
            cof[j] = c;
        }
        const int basecol = (16 * lane < Cc - 16) ? 16 * lane : (Cc - 16);
        // force-drain compiler loads (targets/lens) so vmcnt counts only ours
        asm volatile("s_waitcnt vmcnt(0)" ::: "memory");

        uint4 A0, A1, A2, A3, B0, B1, B2, B3;

#define PROC_ROW(R0_, R1_, R2_, R3_, T_)                                      \
    do {                                                                      \
        uint4 x, y;                                                           \
        {                                                                     \
            __half2 h0, h1, h2, h3, h4, h5, h6, h7;                           \
            const float* fa = (const float*)&(R0_);                           \
            const float* fb = (const float*)&(R1_);                           \
            const float* fc = (const float*)&(R2_);                           \
            const float* fd = (const float*)&(R3_);                           \
            h0.x = __float2half(fa[0]); h0.y = __float2half(fa[1]);           \
            h1.x = __float2half(fa[2]); h1.y = __float2half(fa[3]);           \
            h2.x = __float2half(fb[0]); h2.y = __float2half(fb[1]);           \
            h3.x = __float2half(fb[2]); h3.y = __float2half(fb[3]);           \
            h4.x = __float2half(fc[0]); h4.y = __float2half(fc[1]);           \
            h5.x = __float2half(fc[2]); h5.y = __float2half(fc[3]);           \
            h6.x = __float2half(fd[0]); h6.y = __float2half(fd[1]);           \
            h7.x = __float2half(fd[2]); h7.y = __float2half(fd[3]);           \
            x.x = *(unsigned*)&h0; x.y = *(unsigned*)&h1;                     \
            x.z = *(unsigned*)&h2; x.w = *(unsigned*)&h3;                     \
            y.x = *(unsigned*)&h4; y.y = *(unsigned*)&h5;                     \
            y.z = *(unsigned*)&h6; y.w = *(unsigned*)&h7;                     \
        }                                                                     \
        if (lane < 63) {                                                      \
            uint4* dst = (uint4*)&scratch[p][basecol];                        \
            dst[0] = x; dst[1] = y;                                           \
        }                                                                     \
        const int slot_ = (T_) % RING;                                        \
        float* rr = &ring[slot_ * RSF];                                       \
        _Pragma("unroll")                                                     \
        for (int j = 0; j < 4; ++j) {                                         \
            const int g = lane + 64 * j;                                      \
            if (g < RSF) {                                                    \
                float pv = 0.f;                                               \
                if (g < L) {                                                  \
                    const float lp = __half2float(scratch[p][cof[j]]);        \
                    pv = exp2f((lp + OFF) * LOG2E);                           \
                }                                                             \
                rr[g] = pv;                                                   \
            }                                                                 \
        }                                                                     \
        __threadfence_block();                                                \
        if (lane == 0) vflags[slot_] = (T_);                                  \
    } while (0)

        int t = p;
        if (t < Tb) {
            issue_row(A0, A1, A2, A3,
                      logp + ((size_t)t * Bc + b) * Cc + basecol);
            while (true) {
                // phase A: consume A, refill B
                while ((t - *vconsp) > RING) {}
                {
                    const int tn = (t + NP < Tb) ? t + NP : t;
                    issue_row(B0, B1, B2, B3,
                              logp + ((size_t)tn * Bc + b) * Cc + basecol);
                }
                wait4(A0, A1, A2, A3);
                PROC_ROW(A0, A1, A2, A3, t);
                t += NP;
                if (t >= Tb) break;
                // phase B: consume B, refill A
                while ((t - *vconsp) > RING) {}
                {
                    const int tn = (t + NP < Tb) ? t + NP : t;
                    issue_row(A0, A1, A2, A3,
                              logp + ((size_t)tn * Bc + b) * Cc + basecol);
                }
                wait4(B0, B1, B2, B3);
                PROC_ROW(B0, B1, B2, B3, t);
                t += NP;
                if (t >= Tb) break;
            }
        }
#undef PROC_ROW
    }
}

extern "C" void kernel_launch(void* const* d_in, const int* in_sizes, int n_in,
                              void* d_out, int out_size, void* d_ws, size_t ws_size,
                              hipStream_t stream) {
    const float* logp = (const float*)d_in[0];
    const int* targets = (const int*)d_in[1];
    const int* input_lens = (const int*)d_in[2];
    const int* target_lens = (const int*)d_in[3];
    float* out = (float*)d_out;
    (void)d_ws; (void)ws_size; (void)in_sizes; (void)n_in; (void)out_size;

    (void)hipMemsetAsync(d_out, 0, sizeof(float), stream);
    ctc_fused<<<Bc, 960, 0, stream>>>(logp, targets, input_lens, target_lens, out);
}